// Round 2
// baseline (3750.002 us; speedup 1.0000x reference)
//
#include <hip/hip_runtime.h>

// Persistent-CG rewrite: K (64 MiB) is held in VGPRs (128 regs/thread) across all
// 47 iterations inside ONE cooperative kernel; 2 device-wide barriers per iter.
// Old structure re-streamed K from L3/HBM every iter (k_gemm 34-46us, VALUBusy 13%,
// latency-bound). New floor: 570 MFLOP/iter @157 TF = 3.6us + LDS 2.7us overlapped.

#define NN   4096
#define TT   17
#define PP   16
#define NTOT (NN*TT)          // 69632
#define NIT  47
#define NBLK 256              // 1 block/CU (LDS ~143 KB), cooperative co-residency
#define NTHR 512              // 8 waves; __launch_bounds__(512,2) -> <=256 VGPR
#define EPB  (NTOT/NBLK)      // 272 elems/block for init+update

// ws float offsets
#define O_SSQ  0                    // [16][64] setup ssq partials
#define O_SLOT (O_SSQ + 16*64)      // [256][64] per-iter dot-product slots
#define O_BAR  (O_SLOT + NBLK*64)   // 96 single-use uint barrier slots (128 floats)
#define O_R    (O_BAR + 128)
#define O_P    (O_R + NTOT)
#define O_S    (O_P + NTOT)
#define O_X    (O_S + NTOT)
#define O_W0   (O_X + NTOT)         // 4 k-split partials of K@r

__global__ void k_bzero(float* __restrict__ ws) {
    if (threadIdx.x < 96) ((unsigned*)(ws + O_BAR))[threadIdx.x] = 0u;
}

// Single-use monotonic barrier: no reset -> no generation races. Slots zeroed by
// k_bzero before launch. threadfence = agent release (wb dirty XCD-L2 to coherence
// point); acquire atomic ops invalidate L1/stale-L2 before post-barrier reads.
__device__ __forceinline__ void gridbar(unsigned* bar, int idx) {
    __syncthreads();                     // drains each wave's vmcnt before arrive
    if (threadIdx.x == 0) {
        __threadfence();
        unsigned prev = __hip_atomic_fetch_add(&bar[idx], 1u,
                            __ATOMIC_ACQ_REL, __HIP_MEMORY_SCOPE_AGENT);
        if (prev != (unsigned)(NBLK - 1)) {
            while (__hip_atomic_load(&bar[idx],
                       __ATOMIC_ACQUIRE, __HIP_MEMORY_SCOPE_AGENT) < (unsigned)NBLK) {}
        }
    }
    __syncthreads();                     // thread0's acquire-inv precedes this
}

__global__ __launch_bounds__(NTHR, 2)
void k_cg(const float* __restrict__ Km, const float* __restrict__ yv,
          const float* __restrict__ Zm, const float* __restrict__ noise,
          float* __restrict__ out, float* __restrict__ ws) {
    __shared__ __align__(16) float rl[TT*1024];  // r k-slice [c][1024], 68 KB
    __shared__ float4 p2a[8*TT*17];              // wave partials rows 0-3 (pad 17)
    __shared__ float4 p2b[8*TT*17];              // rows 4-7; stride 17 -> no bank dup
    __shared__ float sm[8][64];
    __shared__ float s_scale[TT], s_rhs[TT], s_al[TT], s_be[TT], s_ap[TT], s_gp[TT];
    __shared__ float redd[TT], redg[TT];

    const int t = threadIdx.x, b = blockIdx.x;
    const int lane = t & 63, w = t >> 6;         // 8 waves
    const int rb = b >> 2, kb = b & 3;           // 64 row-blocks x 4 k-blocks
    const int row0 = rb*64 + w*8;                // 8 rows per wave
    unsigned* bar = (unsigned*)(ws + O_BAR);
    float* r_ = ws + O_R;
    const float s2 = noise[0]*noise[0];

    // ---- one-time: K tile -> registers. lane owns k = kb*1024 + g*256 + lane*4 ----
    float4 kreg[8][4];                            // 128 VGPRs
    {
        const float* Kb = Km + (size_t)row0*NN + kb*1024 + lane*4;
        #pragma unroll
        for (int rr = 0; rr < 8; ++rr)
            #pragma unroll
            for (int g = 0; g < 4; ++g)
                kreg[rr][g] = *(const float4*)(Kb + (size_t)rr*NN + g*256);
    }

    // ---- setup: per-column sum-of-squares partials (blocks 0..15) ----
    if (t < TT) redd[t] = 0.f;
    __syncthreads();
    if (b < 16 && t < 256) {
        int n = b*256 + t;
        float yy = yv[n];
        atomicAdd(&redd[0], yy*yy);
        #pragma unroll
        for (int j = 0; j < PP; ++j) { float v = Zm[n*PP + j]; atomicAdd(&redd[j+1], v*v); }
    }
    __syncthreads();
    if (b < 16 && t < TT) ws[O_SSQ + b*64 + t] = redd[t];
    gridbar(bar, 0);

    // ---- setup: scale/rhs (replicated per block), init r/p/s/x (272 elems) ----
    if (t < TT) {
        float s = 0.f;
        #pragma unroll
        for (int i = 0; i < 16; ++i) s += ws[O_SSQ + i*64 + t];
        float scale, rh;
        if (t == 0) {
            rh = sqrtf(s); if (rh < 1e-10f) rh = 1.f;
            scale = 1.f/rh;
        } else {
            float zn = sqrtf(s);
            float bn = zn/(zn + 1e-10f);
            rh = (bn < 1e-10f) ? 1.f : bn;
            scale = 1.f/((zn + 1e-10f)*rh);
        }
        s_scale[t] = scale; s_rhs[t] = rh;
    }
    __syncthreads();
    if (t < EPB) {
        int e = b*EPB + t, c = e >> 12, n = e & (NN-1);
        float raw = (c == 0) ? yv[n] : Zm[n*PP + (c-1)];
        r_[e] = raw * s_scale[c];
        ws[O_P + e] = 0.f; ws[O_S + e] = 0.f; ws[O_X + e] = 0.f;
    }
    gridbar(bar, 1);

    // ---- 47 pipelined-CG iterations ----
    for (int it = 0; it < NIT; ++it) {
        // stage r[c][kb*1024..+1024) -> LDS; unrolled so all 9 loads are in flight
        {
            const float* rs = r_ + kb*1024;
            #pragma unroll
            for (int q = 0; q < 8; ++q) {
                int v = q*NTHR + t, c = v >> 8, k4 = (v & 255)*4;
                *(float4*)(rl + c*1024 + k4) = *(const float4*)(rs + c*NN + k4);
            }
            if (t < 256) {
                int v = 8*NTHR + t, c = v >> 8, k4 = (v & 255)*4;
                *(float4*)(rl + c*1024 + k4) = *(const float4*)(rs + c*NN + k4);
            }
        }
        if (t < TT) { redd[t] = 0.f; redg[t] = 0.f; }
        __syncthreads();

        // per column: 4x ds_read_b128 (stride-16B, conflict-free) + 128 fmac into
        // 8 row-accs; 2-stage butterfly (64->16 classes); stash to padded p2
        const float* rc0 = rl + lane*4;
        for (int c = 0; c < TT; ++c) {
            const float* rc = rc0 + c*1024;
            float acc[8];
            #pragma unroll
            for (int rr = 0; rr < 8; ++rr) acc[rr] = 0.f;
            #pragma unroll
            for (int g = 0; g < 4; ++g) {
                float4 rv = *(const float4*)(rc + g*256);
                #pragma unroll
                for (int rr = 0; rr < 8; ++rr)
                    acc[rr] += kreg[rr][g].x*rv.x + kreg[rr][g].y*rv.y
                             + kreg[rr][g].z*rv.z + kreg[rr][g].w*rv.w;
            }
            #pragma unroll
            for (int rr = 0; rr < 8; ++rr) {
                float v2 = acc[rr];
                v2 += __shfl_xor(v2, 32, 64);
                v2 += __shfl_xor(v2, 16, 64);
                acc[rr] = v2;
            }
            if (lane < 16) {
                p2a[(w*TT + c)*17 + lane] = make_float4(acc[0], acc[1], acc[2], acc[3]);
                p2b[(w*TT + c)*17 + lane] = make_float4(acc[4], acc[5], acc[6], acc[7]);
            }
        }
        __syncthreads();

        // finish: t<136 -> (w2,c2): sum 16 lane-classes, write w-partial, dot prods
        if (t < 8*TT) {
            int w2 = t / TT, c2 = t % TT;        // (w2*TT + c2) == t
            float4 sa = make_float4(0.f,0.f,0.f,0.f), sb = make_float4(0.f,0.f,0.f,0.f);
            #pragma unroll
            for (int i = 0; i < 16; ++i) {
                float4 u = p2a[t*17 + i];
                sa.x += u.x; sa.y += u.y; sa.z += u.z; sa.w += u.w;
                float4 v2 = p2b[t*17 + i];
                sb.x += v2.x; sb.y += v2.y; sb.z += v2.z; sb.w += v2.w;
            }
            int row = rb*64 + w2*8;
            float* wp = ws + O_W0 + kb*NTOT;
            *(float4*)(wp + c2*NN + row)     = sa;
            *(float4*)(wp + c2*NN + row + 4) = sb;
            float4 ra  = *(const float4*)(r_ + c2*NN + row);
            float4 rb4 = *(const float4*)(r_ + c2*NN + row + 4);
            float dp = ra.x*sa.x + ra.y*sa.y + ra.z*sa.z + ra.w*sa.w
                     + rb4.x*sb.x + rb4.y*sb.y + rb4.z*sb.z + rb4.w*sb.w;
            atomicAdd(&redd[c2], dp);
            if (kb == 0) {
                float gp = ra.x*ra.x + ra.y*ra.y + ra.z*ra.z + ra.w*ra.w
                         + rb4.x*rb4.x + rb4.y*rb4.y + rb4.z*rb4.z + rb4.w*rb4.w;
                atomicAdd(&redg[c2], gp);
            }
        }
        __syncthreads();
        if (t < TT) {
            ws[O_SLOT + b*64 + t]      = redd[t];
            ws[O_SLOT + b*64 + 32 + t] = (kb == 0) ? redg[t] : 0.f;
        }
        gridbar(bar, 2 + 2*it);

        // phase B: alpha/beta replicated in every block (saves a 3rd barrier),
        // then this block's 272-elem p/s/x/r update
        {
            int seg = t >> 6, j = t & 63;
            float s = 0.f;
            if (j < TT || (j >= 32 && j < 32 + TT)) {
                #pragma unroll
                for (int i = 0; i < 32; ++i)
                    s += ws[O_SLOT + (seg*32 + i)*64 + j];
            }
            sm[seg][j] = s;
        }
        __syncthreads();
        if (t < TT) {
            float del = 0.f, gam = 0.f;
            #pragma unroll
            for (int g = 0; g < 8; ++g) { del += sm[g][t]; gam += sm[g][32 + t]; }
            float delta = del + s2*gam;           // r^T (K + s2 I) r
            float beta = 0.f, D = delta;
            if (it > 0) {
                float gp = s_gp[t];
                beta = (fabsf(gp) < 1e-30f) ? 0.f : gam/gp;
                float ap = s_ap[t];
                D = delta - ((fabsf(ap) < 1e-30f) ? 0.f : beta*gam/ap);
            }
            float alpha = (fabsf(D) < 1e-30f) ? 0.f : gam/D;
            s_al[t] = alpha; s_be[t] = beta; s_ap[t] = alpha; s_gp[t] = gam;
        }
        __syncthreads();
        if (t < EPB) {
            int e = b*EPB + t, c = e >> 12, n = e & (NN-1);
            float al = s_al[c], be = s_be[c];
            float rv = r_[e];
            float wv = ws[O_W0 + e] + ws[O_W0 + NTOT + e]
                     + ws[O_W0 + 2*NTOT + e] + ws[O_W0 + 3*NTOT + e] + s2*rv;
            float pn = rv + be*ws[O_P + e];
            float sn = wv + be*ws[O_S + e];
            float xn = ws[O_X + e] + al*pn;
            float rn = rv - al*sn;
            ws[O_P + e] = pn; ws[O_S + e] = sn; ws[O_X + e] = xn; r_[e] = rn;
            if (it == NIT-1) out[n*TT + c] = xn * s_rhs[c];
        }
        gridbar(bar, 3 + 2*it);
    }
}

extern "C" void kernel_launch(void* const* d_in, const int* in_sizes, int n_in,
                              void* d_out, int out_size, void* d_ws, size_t ws_size,
                              hipStream_t stream) {
    const float* Km    = (const float*)d_in[0];
    const float* yv    = (const float*)d_in[1];
    const float* Zm    = (const float*)d_in[2];
    const float* noise = (const float*)d_in[3];
    float* out = (float*)d_out;
    float* ws  = (float*)d_ws;

    k_bzero<<<1, 128, 0, stream>>>(ws);
    void* args[] = {(void*)&Km, (void*)&yv, (void*)&Zm, (void*)&noise,
                    (void*)&out, (void*)&ws};
    hipLaunchCooperativeKernel((const void*)k_cg, dim3(NBLK), dim3(NTHR),
                               args, 0, stream);
}

// Round 3
// 2337.954 us; speedup vs baseline: 1.6040x; 1.6040x over previous
//
#include <hip/hip_runtime.h>

// Persistent-CG: K (64 MiB) held in VGPRs (128 regs/thread) across all 47 iters in
// ONE cooperative kernel; 2 grid barriers/iter.
// R2 post-mortem: passed @3650us, VALUBusy 7.7% -> ~3.3ms in 96 barriers (~35us ea).
// Cause: ACQUIRE spin-poll emitted buffer_inv per poll (L2 invalidate storm across
// all XCDs) + ACQ_REL arrivals emitted wbl2+inv per block + 256 RMWs on one line.
// R3 fix: monotonic 2-level tree barrier, RELAXED atomics, exactly one release
// fence (wbl2) + one acquire fence (inv) per block per barrier, s_sleep backoff.

#define NN   4096
#define TT   17
#define PP   16
#define NTOT (NN*TT)          // 69632
#define NIT  47
#define NBLK 256              // 1 block/CU (LDS ~143 KB), cooperative co-residency
#define NTHR 512              // 8 waves; __launch_bounds__(512,2) -> <=256 VGPR
#define EPB  (NTOT/NBLK)      // 272 elems/block for init+update

// ws float offsets
#define O_SSQ  0                    // [16][64] setup ssq partials
#define O_SLOT (O_SSQ + 16*64)      // [256][64] per-iter dot-product slots
#define O_BAR  (O_SLOT + NBLK*64)   // 17 cachelines x 32 uints: monotonic tree barrier
#define O_R    (O_BAR + 576)
#define O_P    (O_R + NTOT)
#define O_S    (O_P + NTOT)
#define O_X    (O_S + NTOT)
#define O_W0   (O_X + NTOT)         // 4 k-split partials of K@r

__global__ void k_bzero(float* __restrict__ ws) {
    if (threadIdx.x < 544) ((unsigned*)(ws + O_BAR))[threadIdx.x] = 0u;
}

// Monotonic two-level grid barrier. 16 leaves (128B-line-separated) -> 1 root.
// RELAXED arrivals/polls (no per-op cache maintenance on gfx950); visibility via
// ONE agent release fence (wbl2: flush dirty XCD-L2 to coherence point) before
// arrival and ONE acquire fence (inv) after the root reaches its target.
// Counters never reset: phase p waits for root >= 16*(p+1). Max 96*16 < 2^32.
__device__ __forceinline__ void gridbar(unsigned* bar, int phase, int b) {
    __syncthreads();                     // all waves' work complete before arrive
    if (threadIdx.x == 0) {
        unsigned* leaf = bar + ((b >> 4) << 5);   // 16 blocks per leaf line
        unsigned* root = bar + 512;
        __builtin_amdgcn_fence(__ATOMIC_RELEASE, "agent");
        unsigned prev = __hip_atomic_fetch_add(leaf, 1u,
                            __ATOMIC_RELAXED, __HIP_MEMORY_SCOPE_AGENT);
        if (prev == (unsigned)(phase*16 + 15))    // leaf complete -> promote
            __hip_atomic_fetch_add(root, 1u,
                __ATOMIC_RELAXED, __HIP_MEMORY_SCOPE_AGENT);
        const unsigned target = (unsigned)((phase + 1) * 16);
        while (__hip_atomic_load(root, __ATOMIC_RELAXED,
                                 __HIP_MEMORY_SCOPE_AGENT) < target)
            __builtin_amdgcn_s_sleep(1);
        __builtin_amdgcn_fence(__ATOMIC_ACQUIRE, "agent");
    }
    __syncthreads();                     // thread0's acquire-inv precedes reads
}

__global__ __launch_bounds__(NTHR, 2)
void k_cg(const float* __restrict__ Km, const float* __restrict__ yv,
          const float* __restrict__ Zm, const float* __restrict__ noise,
          float* __restrict__ out, float* __restrict__ ws) {
    __shared__ __align__(16) float rl[TT*1024];  // r k-slice [c][1024], 68 KB
    __shared__ float4 p2a[8*TT*17];              // wave partials rows 0-3 (pad 17)
    __shared__ float4 p2b[8*TT*17];              // rows 4-7; stride 17 -> no bank dup
    __shared__ float sm[8][64];
    __shared__ float s_scale[TT], s_rhs[TT], s_al[TT], s_be[TT], s_ap[TT], s_gp[TT];
    __shared__ float redd[TT], redg[TT];

    const int t = threadIdx.x, b = blockIdx.x;
    const int lane = t & 63, w = t >> 6;         // 8 waves
    const int rb = b >> 2, kb = b & 3;           // 64 row-blocks x 4 k-blocks
    const int row0 = rb*64 + w*8;                // 8 rows per wave
    unsigned* bar = (unsigned*)(ws + O_BAR);
    float* r_ = ws + O_R;
    const float s2 = noise[0]*noise[0];
    int ph = 0;                                  // barrier phase counter

    // ---- one-time: K tile -> registers. lane owns k = kb*1024 + g*256 + lane*4 ----
    float4 kreg[8][4];                            // 128 VGPRs
    {
        const float* Kb = Km + (size_t)row0*NN + kb*1024 + lane*4;
        #pragma unroll
        for (int rr = 0; rr < 8; ++rr)
            #pragma unroll
            for (int g = 0; g < 4; ++g)
                kreg[rr][g] = *(const float4*)(Kb + (size_t)rr*NN + g*256);
    }

    // ---- setup: per-column sum-of-squares partials (blocks 0..15) ----
    if (t < TT) redd[t] = 0.f;
    __syncthreads();
    if (b < 16 && t < 256) {
        int n = b*256 + t;
        float yy = yv[n];
        atomicAdd(&redd[0], yy*yy);
        #pragma unroll
        for (int j = 0; j < PP; ++j) { float v = Zm[n*PP + j]; atomicAdd(&redd[j+1], v*v); }
    }
    __syncthreads();
    if (b < 16 && t < TT) ws[O_SSQ + b*64 + t] = redd[t];
    gridbar(bar, ph++, b);

    // ---- setup: scale/rhs (replicated per block), init r/p/s/x (272 elems) ----
    if (t < TT) {
        float s = 0.f;
        #pragma unroll
        for (int i = 0; i < 16; ++i) s += ws[O_SSQ + i*64 + t];
        float scale, rh;
        if (t == 0) {
            rh = sqrtf(s); if (rh < 1e-10f) rh = 1.f;
            scale = 1.f/rh;
        } else {
            float zn = sqrtf(s);
            float bn = zn/(zn + 1e-10f);
            rh = (bn < 1e-10f) ? 1.f : bn;
            scale = 1.f/((zn + 1e-10f)*rh);
        }
        s_scale[t] = scale; s_rhs[t] = rh;
    }
    __syncthreads();
    if (t < EPB) {
        int e = b*EPB + t, c = e >> 12, n = e & (NN-1);
        float raw = (c == 0) ? yv[n] : Zm[n*PP + (c-1)];
        r_[e] = raw * s_scale[c];
        ws[O_P + e] = 0.f; ws[O_S + e] = 0.f; ws[O_X + e] = 0.f;
    }
    gridbar(bar, ph++, b);

    // ---- 47 pipelined-CG iterations ----
    for (int it = 0; it < NIT; ++it) {
        // stage r[c][kb*1024..+1024) -> LDS; unrolled so all 9 loads are in flight
        {
            const float* rs = r_ + kb*1024;
            #pragma unroll
            for (int q = 0; q < 8; ++q) {
                int v = q*NTHR + t, c = v >> 8, k4 = (v & 255)*4;
                *(float4*)(rl + c*1024 + k4) = *(const float4*)(rs + c*NN + k4);
            }
            if (t < 256) {
                int v = 8*NTHR + t, c = v >> 8, k4 = (v & 255)*4;
                *(float4*)(rl + c*1024 + k4) = *(const float4*)(rs + c*NN + k4);
            }
        }
        if (t < TT) { redd[t] = 0.f; redg[t] = 0.f; }
        __syncthreads();

        // per column: 4x ds_read_b128 (stride-16B, conflict-free) + 128 fmac into
        // 8 row-accs; 2-stage butterfly (64->16 classes); stash to padded p2
        const float* rc0 = rl + lane*4;
        for (int c = 0; c < TT; ++c) {
            const float* rc = rc0 + c*1024;
            float acc[8];
            #pragma unroll
            for (int rr = 0; rr < 8; ++rr) acc[rr] = 0.f;
            #pragma unroll
            for (int g = 0; g < 4; ++g) {
                float4 rv = *(const float4*)(rc + g*256);
                #pragma unroll
                for (int rr = 0; rr < 8; ++rr)
                    acc[rr] += kreg[rr][g].x*rv.x + kreg[rr][g].y*rv.y
                             + kreg[rr][g].z*rv.z + kreg[rr][g].w*rv.w;
            }
            #pragma unroll
            for (int rr = 0; rr < 8; ++rr) {
                float v2 = acc[rr];
                v2 += __shfl_xor(v2, 32, 64);
                v2 += __shfl_xor(v2, 16, 64);
                acc[rr] = v2;
            }
            if (lane < 16) {
                p2a[(w*TT + c)*17 + lane] = make_float4(acc[0], acc[1], acc[2], acc[3]);
                p2b[(w*TT + c)*17 + lane] = make_float4(acc[4], acc[5], acc[6], acc[7]);
            }
        }
        __syncthreads();

        // finish: t<136 -> (w2,c2): sum 16 lane-classes, write w-partial, dot prods
        if (t < 8*TT) {
            int w2 = t / TT, c2 = t % TT;        // (w2*TT + c2) == t
            float4 sa = make_float4(0.f,0.f,0.f,0.f), sb = make_float4(0.f,0.f,0.f,0.f);
            #pragma unroll
            for (int i = 0; i < 16; ++i) {
                float4 u = p2a[t*17 + i];
                sa.x += u.x; sa.y += u.y; sa.z += u.z; sa.w += u.w;
                float4 v2 = p2b[t*17 + i];
                sb.x += v2.x; sb.y += v2.y; sb.z += v2.z; sb.w += v2.w;
            }
            int row = rb*64 + w2*8;
            float* wp = ws + O_W0 + kb*NTOT;
            *(float4*)(wp + c2*NN + row)     = sa;
            *(float4*)(wp + c2*NN + row + 4) = sb;
            float4 ra  = *(const float4*)(r_ + c2*NN + row);
            float4 rb4 = *(const float4*)(r_ + c2*NN + row + 4);
            float dp = ra.x*sa.x + ra.y*sa.y + ra.z*sa.z + ra.w*sa.w
                     + rb4.x*sb.x + rb4.y*sb.y + rb4.z*sb.z + rb4.w*sb.w;
            atomicAdd(&redd[c2], dp);
            if (kb == 0) {
                float gp = ra.x*ra.x + ra.y*ra.y + ra.z*ra.z + ra.w*ra.w
                         + rb4.x*rb4.x + rb4.y*rb4.y + rb4.z*rb4.z + rb4.w*rb4.w;
                atomicAdd(&redg[c2], gp);
            }
        }
        __syncthreads();
        if (t < TT) {
            ws[O_SLOT + b*64 + t]      = redd[t];
            ws[O_SLOT + b*64 + 32 + t] = (kb == 0) ? redg[t] : 0.f;
        }
        gridbar(bar, ph++, b);

        // phase B: alpha/beta replicated in every block (saves a 3rd barrier),
        // then this block's 272-elem p/s/x/r update
        {
            int seg = t >> 6, j = t & 63;
            float s = 0.f;
            if (j < TT || (j >= 32 && j < 32 + TT)) {
                #pragma unroll
                for (int i = 0; i < 32; ++i)
                    s += ws[O_SLOT + (seg*32 + i)*64 + j];
            }
            sm[seg][j] = s;
        }
        __syncthreads();
        if (t < TT) {
            float del = 0.f, gam = 0.f;
            #pragma unroll
            for (int g = 0; g < 8; ++g) { del += sm[g][t]; gam += sm[g][32 + t]; }
            float delta = del + s2*gam;           // r^T (K + s2 I) r
            float beta = 0.f, D = delta;
            if (it > 0) {
                float gp = s_gp[t];
                beta = (fabsf(gp) < 1e-30f) ? 0.f : gam/gp;
                float ap = s_ap[t];
                D = delta - ((fabsf(ap) < 1e-30f) ? 0.f : beta*gam/ap);
            }
            float alpha = (fabsf(D) < 1e-30f) ? 0.f : gam/D;
            s_al[t] = alpha; s_be[t] = beta; s_ap[t] = alpha; s_gp[t] = gam;
        }
        __syncthreads();
        if (t < EPB) {
            int e = b*EPB + t, c = e >> 12, n = e & (NN-1);
            float al = s_al[c], be = s_be[c];
            float rv = r_[e];
            float wv = ws[O_W0 + e] + ws[O_W0 + NTOT + e]
                     + ws[O_W0 + 2*NTOT + e] + ws[O_W0 + 3*NTOT + e] + s2*rv;
            float pn = rv + be*ws[O_P + e];
            float sn = wv + be*ws[O_S + e];
            float xn = ws[O_X + e] + al*pn;
            float rn = rv - al*sn;
            ws[O_P + e] = pn; ws[O_S + e] = sn; ws[O_X + e] = xn; r_[e] = rn;
            if (it == NIT-1) out[n*TT + c] = xn * s_rhs[c];
        }
        gridbar(bar, ph++, b);
    }
}

extern "C" void kernel_launch(void* const* d_in, const int* in_sizes, int n_in,
                              void* d_out, int out_size, void* d_ws, size_t ws_size,
                              hipStream_t stream) {
    const float* Km    = (const float*)d_in[0];
    const float* yv    = (const float*)d_in[1];
    const float* Zm    = (const float*)d_in[2];
    const float* noise = (const float*)d_in[3];
    float* out = (float*)d_out;
    float* ws  = (float*)d_ws;

    k_bzero<<<1, 576, 0, stream>>>(ws);
    void* args[] = {(void*)&Km, (void*)&yv, (void*)&Zm, (void*)&noise,
                    (void*)&out, (void*)&ws};
    hipLaunchCooperativeKernel((const void*)k_cg, dim3(NBLK), dim3(NTHR),
                               args, 0, stream);
}